// Round 17
// baseline (175.721 us; speedup 1.0000x reference)
//
#include <hip/hip_runtime.h>
#include <hip/hip_fp16.h>
#include <math.h>

#define HID 32
#define NFEAT 100
#define CHUNK 4096   // edges per sort chunk (391 chunks = sort parallelism, R8 lesson)
#define NCMAX 512    // max chunks (E/CHUNK = 391)
#define NBMAX 1600   // max buckets (N/64 = 1563)
#define LOCB 64      // target nodes per bucket (R11 lesson: 1563 blocks needed for latency hiding)
#define LCAP 1408    // LDS edge capacity per bucket (mean 1024, sd 32 -> +12 sigma)

#define ALIGN256(x) ((((size_t)(x)) + 255) & ~(size_t)255)

typedef _Float16 half8 __attribute__((ext_vector_type(8)));
typedef float f32x4 __attribute__((ext_vector_type(4)));

__device__ __forceinline__ float2 h2f(unsigned int u) {
    return __half22float2(*(__half2*)&u);
}
__device__ __forceinline__ float4 h4_to_f4(uint2 u) {
    float2 a = h2f(u.x), b = h2f(u.y);
    return make_float4(a.x, a.y, b.x, b.y);
}

// 8-lane sum reduction via DPP (proven R7-R15); all 8 lanes get the sum.
__device__ __forceinline__ float dpp_sum8(float x) {
    int v = __float_as_int(x);
    x += __int_as_float(__builtin_amdgcn_update_dpp(0, v, 0xB1, 0xF, 0xF, true));
    v = __float_as_int(x);
    x += __int_as_float(__builtin_amdgcn_update_dpp(0, v, 0x4E, 0xF, 0xF, true));
    v = __float_as_int(x);
    x += __int_as_float(__builtin_amdgcn_update_dpp(0, v, 0x141, 0xF, 0xF, true));
    return x;
}

// ================= K1 (MFMA): xn = fp16(x/||x||); y = (x.w2row0, x.w2row1) fp32 ===========
__global__ __launch_bounds__(256) void k1(
    const float* __restrict__ X, const float* __restrict__ w1,
    const float* __restrict__ b1, const float* __restrict__ w2,
    __half* __restrict__ xh, float2* __restrict__ yv, int N)
{
    __shared__ __align__(16) char smem[26112];
    const int tid = threadIdx.x;
    const int blk = blockIdx.x;
    _Float16* w1h = (_Float16*)smem;              // [32][136]
    _Float16* xsH = (_Float16*)(smem + 8704);     // [64][136]
    {
        int* w1hI = (int*)w1h; int* xsHI = (int*)xsH;
        for (int i = tid; i < 1728; i += 256) {      // zero K-pad: 96 rows * 18 ints
            int row = i / 18, c2 = i % 18;
            if (row < 32) w1hI[row * 68 + 50 + c2] = 0;
            else          xsHI[(row - 32) * 68 + 50 + c2] = 0;
        }
    }
    const float4* w14 = (const float4*)w1;          // 800 float4
    for (int i = tid; i < 800; i += 256) {
        float4 v = w14[i];
        int idx = i * 4, h = idx / NFEAT, k = idx % NFEAT;
        __half2* d = (__half2*)&w1h[h * 136 + k];
        d[0] = __floats2half2_rn(v.x, v.y);
        d[1] = __floats2half2_rn(v.z, v.w);
    }
    const int n0 = blk * 64;
    const float4* X4 = (const float4*)X;            // row = 25 float4
    for (int i = tid; i < 1600; i += 256) {
        int rr = i / 25, qq = i % 25;
        int node = n0 + rr;
        float4 v = (node < N) ? X4[(size_t)node * 25 + qq] : make_float4(0.f, 0.f, 0.f, 0.f);
        __half2* d = (__half2*)&xsH[rr * 136 + qq * 4];
        d[0] = __floats2half2_rn(v.x, v.y);
        d[1] = __floats2half2_rn(v.z, v.w);
    }
    __syncthreads();

    const int lane = tid & 63;
    const int wvv  = tid >> 6;    // node tile 0..3 (16 nodes each)
    const int mrow = lane & 15;
    const int kgrp = lane >> 4;   // 0..3
    const _Float16* bp = &xsH[(wvv * 16 + mrow) * 136 + kgrp * 8];
    const _Float16* a0 = &w1h[mrow * 136 + kgrp * 8];
    const _Float16* a1 = &w1h[(16 + mrow) * 136 + kgrp * 8];
    f32x4 acc0 = {0.f, 0.f, 0.f, 0.f}, acc1 = {0.f, 0.f, 0.f, 0.f};
    #pragma unroll
    for (int ks = 0; ks < 4; ++ks) {
        half8 bf  = *(const half8*)(bp + ks * 32);
        half8 af0 = *(const half8*)(a0 + ks * 32);
        half8 af1 = *(const half8*)(a1 + ks * 32);
        acc0 = __builtin_amdgcn_mfma_f32_16x16x32_f16(af0, bf, acc0, 0, 0, 0);
        acc1 = __builtin_amdgcn_mfma_f32_16x16x32_f16(af1, bf, acc1, 0, 0, 0);
    }
    // D[m][n]: n = lane&15 (node), m = kgrp*4 + reg (h); acc1 -> h+16
    float v[8]; float ssq = 0.f;
    #pragma unroll
    for (int rr = 0; rr < 4; ++rr) {
        v[rr]     = fmaxf(acc0[rr] + b1[kgrp * 4 + rr], 0.f);
        v[4 + rr] = fmaxf(acc1[rr] + b1[16 + kgrp * 4 + rr], 0.f);
        ssq += v[rr] * v[rr] + v[4 + rr] * v[4 + rr];
    }
    ssq += __shfl_xor(ssq, 16, 64);
    ssq += __shfl_xor(ssq, 32, 64);
    const float inv = 1.f / fmaxf(sqrtf(ssq), 1e-12f);

    // y partials: lane holds features kgrp*4+rr and 16+kgrp*4+rr
    float y0 = 0.f, y1 = 0.f;
    #pragma unroll
    for (int rr = 0; rr < 4; ++rr) {
        y0 += v[rr] * w2[kgrp * 4 + rr]       + v[4 + rr] * w2[16 + kgrp * 4 + rr];
        y1 += v[rr] * w2[HID + kgrp * 4 + rr] + v[4 + rr] * w2[HID + 16 + kgrp * 4 + rr];
    }
    y0 += __shfl_xor(y0, 16, 64); y0 += __shfl_xor(y0, 32, 64);
    y1 += __shfl_xor(y1, 16, 64); y1 += __shfl_xor(y1, 32, 64);

    const int node = n0 + wvv * 16 + mrow;
    if (node < N) {
        __half2 p0 = __floats2half2_rn(v[0] * inv, v[1] * inv);
        __half2 p1 = __floats2half2_rn(v[2] * inv, v[3] * inv);
        __half2 p2 = __floats2half2_rn(v[4] * inv, v[5] * inv);
        __half2 p3 = __floats2half2_rn(v[6] * inv, v[7] * inv);
        uint2 u0; u0.x = *(unsigned int*)&p0; u0.y = *(unsigned int*)&p1;
        uint2 u1; u1.x = *(unsigned int*)&p2; u1.y = *(unsigned int*)&p3;
        *(uint2*)&xh[(size_t)node * HID + kgrp * 4] = u0;
        *(uint2*)&xh[(size_t)node * HID + 16 + kgrp * 4] = u1;
        if (kgrp == 0) yv[node] = make_float2(y0, y1);
    }
}

// ================= K_sort: chunk-local counting sort, 512 threads =========================
__global__ __launch_bounds__(512) void k_sort(
    const int* __restrict__ ei,
    int* __restrict__ binned, unsigned short* __restrict__ offU,
    int E, int NB, int NC)
{
    __shared__ int tgt[CHUNK];       // 16 KB
    __shared__ int hist[NBMAX];      // 6.4 KB
    __shared__ int off[NBMAX];       // 6.4 KB
    const int tid = threadIdx.x;
    const int c = blockIdx.x;
    const int start = c * CHUNK;
    const int end = min(start + CHUNK, E);
    const int n = end - start;

    for (int b = tid; b < NB; b += 512) hist[b] = 0;
    for (int i = tid * 4; i < n; i += 2048) {
        if (i + 3 < n) {
            int4 t4 = *(const int4*)(ei + E + start + i);
            tgt[i] = t4.x; tgt[i + 1] = t4.y; tgt[i + 2] = t4.z; tgt[i + 3] = t4.w;
        } else {
            for (int k = 0; k < 4 && i + k < n; ++k) tgt[i + k] = ei[E + start + i + k];
        }
    }
    __syncthreads();
    for (int i = tid; i < n; i += 512) atomicAdd(&hist[tgt[i] >> 6], 1);
    __syncthreads();
    if (tid < 64) {   // wave 0: exclusive scan, 64 buckets/round with carry
        int carry = 0;
        for (int rr = 0; rr * 64 < NB; ++rr) {
            int b = rr * 64 + tid;
            int v = (b < NB) ? hist[b] : 0;
            int x = v;
            #pragma unroll
            for (int dd = 1; dd < 64; dd <<= 1) {
                int y = __shfl_up(x, dd, 64);
                if (tid >= dd) x += y;
            }
            if (b < NB) off[b] = carry + x - v;
            carry += __shfl(x, 63, 64);
        }
    }
    __syncthreads();
    const size_t urow = (size_t)c * (NB + 1);
    for (int b = tid; b < NB; b += 512) {
        offU[urow + b] = (unsigned short)off[b];   // coalesced u16 writes
        hist[b] = off[b];                           // reuse as local cursor
    }
    if (tid == 0) offU[urow + NB] = (unsigned short)n;
    __syncthreads();
    for (int i = tid; i < n; i += 512) {
        const int t = tgt[i];
        const int b = t >> 6;
        const int pos = atomicAdd(&hist[b], 1);
        binned[start + pos] = ei[start + i] | ((t & 63) << 17);  // src<2^17, local 6 bits
    }
}

// ===== Fused: y-formulation gather with 4-DEEP pipeline (16 outstanding loads/wave) =======
// 256 threads (4 waves) / 64-node bucket; 8 lanes/edge; named slot-states (no arrays).
__global__ __launch_bounds__(256) void k_fused(
    const int* __restrict__ binned, const unsigned short* __restrict__ offU,
    const __half* __restrict__ xh, const float2* __restrict__ yv,
    const float* __restrict__ pbeta, const float* __restrict__ b2,
    float* __restrict__ out, int N, int NB, int NC)
{
    __shared__ unsigned short b0s[NCMAX], b1s[NCMAX];
    __shared__ int seg[NCMAX + 1];
    __shared__ int cnt[LOCB], cur[LOCB];
    __shared__ int led[LCAP], led2[LCAP];
    const int tid  = threadIdx.x;
    const int lane = tid & 63;
    const int wv   = tid >> 6;   // wave 0..3
    const int g    = lane & 7;   // feature slice: halfs g*4 .. g*4+3
    const int sub  = lane >> 3;  // edge slot 0..7
    const int b    = blockIdx.x;
    const int R    = NB + 1;
    const float beta = *pbeta;
    const float bb0 = b2[0], bb1 = b2[1];

    for (int c = tid; c < NC; c += 256) {
        const size_t base = (size_t)c * R + b;
        b0s[c] = offU[base];
        b1s[c] = offU[base + 1];
    }
    if (tid < LOCB) cnt[tid] = 0;
    __syncthreads();

    // exclusive scan of segment lengths (wave 0)
    if (tid < 64) {
        int carry = 0;
        for (int rr = 0; rr * 64 < NC; ++rr) {
            int c = rr * 64 + tid;
            int v = (c < NC) ? (int)b1s[c] - (int)b0s[c] : 0;
            int x = v;
            #pragma unroll
            for (int dd = 1; dd < 64; dd <<= 1) {
                int y = __shfl_up(x, dd, 64);
                if (tid >= dd) x += y;
            }
            if (c < NC) seg[c] = carry + x - v;
            carry += __shfl(x, 63, 64);
        }
        if (tid == 0) seg[NC] = carry;
    }
    __syncthreads();
    const int sz = min(seg[NC], LCAP);

    // thread-per-segment concat (~2.6 edges/segment)
    for (int c = tid; c < NC; c += 256) {
        const int b0 = (int)b0s[c];
        const int len = (int)b1s[c] - b0;
        const int gbase = c * CHUNK + b0;
        const int sp = seg[c];
        for (int j = 0; j < len; ++j) {
            const int idx = sp + j;
            if (idx < LCAP) {
                const int w = binned[gbase + j];
                led[idx] = w;
                atomicAdd(&cnt[w >> 17], 1);
            }
        }
    }
    __syncthreads();
    if (tid < 64) {   // exclusive scan of 64 counts
        int v = cnt[tid], x = v;
        #pragma unroll
        for (int dd = 1; dd < 64; dd <<= 1) {
            int y = __shfl_up(x, dd, 64);
            if (tid >= dd) x += y;
        }
        cur[tid] = x - v;
    }
    __syncthreads();
    // reorder into led2, grouped by local node
    for (int i = tid; i < sz; i += 256) {
        const int w = led[i];
        const int pos = atomicAdd(&cur[w >> 17], 1);
        led2[pos] = w & 0x1FFFF;
    }
    __syncthreads();

    // dual-node gather, 4-deep pipeline: slots A/B/C/D per chain = 16 outstanding loads/wave
    for (int l0 = wv; l0 < 32; l0 += 4) {
        const int l1 = l0 + 32;
        const int node0 = b * LOCB + l0;
        const int node1 = b * LOCB + l1;
        const bool v0 = node0 < N, v1 = node1 < N;
        const int nr0 = v0 ? node0 : N - 1;
        const int nr1 = v1 ? node1 : N - 1;

        const uint2 ut0 = *(const uint2*)(xh + (size_t)nr0 * HID + g * 4);
        const uint2 ut1 = *(const uint2*)(xh + (size_t)nr1 * HID + g * 4);
        const float4 xt0 = h4_to_f4(ut0);
        const float4 xt1 = h4_to_f4(ut1);

        const int deg0 = cnt[l0], deg1 = cnt[l1];
        const int st0 = cur[l0] - deg0, st1 = cur[l1] - deg1;

        float ds0 = 0.f, a00 = 0.f, a01 = 0.f;
        float ds1 = 0.f, a10 = 0.f, a11 = 0.f;

        // ---- prologue: load slots A (sub), B (+8), C (+16), D (+24) for both chains ----
        bool okA0 = sub < deg0,      okA1 = sub < deg1;
        bool okB0 = sub + 8 < deg0,  okB1 = sub + 8 < deg1;
        bool okC0 = sub + 16 < deg0, okC1 = sub + 16 < deg1;
        bool okD0 = sub + 24 < deg0, okD1 = sub + 24 < deg1;
        int sA0 = led2[okA0 ? st0 + sub : 0];      sA0 = okA0 ? sA0 : 0;
        int sA1 = led2[okA1 ? st1 + sub : 0];      sA1 = okA1 ? sA1 : 0;
        int sB0 = led2[okB0 ? st0 + sub + 8 : 0];  sB0 = okB0 ? sB0 : 0;
        int sB1 = led2[okB1 ? st1 + sub + 8 : 0];  sB1 = okB1 ? sB1 : 0;
        int sC0 = led2[okC0 ? st0 + sub + 16 : 0]; sC0 = okC0 ? sC0 : 0;
        int sC1 = led2[okC1 ? st1 + sub + 16 : 0]; sC1 = okC1 ? sC1 : 0;
        int sD0 = led2[okD0 ? st0 + sub + 24 : 0]; sD0 = okD0 ? sD0 : 0;
        int sD1 = led2[okD1 ? st1 + sub + 24 : 0]; sD1 = okD1 ? sD1 : 0;
        uint2 uA0 = *(const uint2*)(xh + (size_t)sA0 * HID + g * 4);
        uint2 uA1 = *(const uint2*)(xh + (size_t)sA1 * HID + g * 4);
        uint2 uB0 = *(const uint2*)(xh + (size_t)sB0 * HID + g * 4);
        uint2 uB1 = *(const uint2*)(xh + (size_t)sB1 * HID + g * 4);
        uint2 uC0 = *(const uint2*)(xh + (size_t)sC0 * HID + g * 4);
        uint2 uC1 = *(const uint2*)(xh + (size_t)sC1 * HID + g * 4);
        uint2 uD0 = *(const uint2*)(xh + (size_t)sD0 * HID + g * 4);
        uint2 uD1 = *(const uint2*)(xh + (size_t)sD1 * HID + g * 4);
        float2 yA0 = yv[sA0], yA1 = yv[sA1];
        float2 yB0 = yv[sB0], yB1 = yv[sB1];
        float2 yC0 = yv[sC0], yC1 = yv[sC1];
        float2 yD0 = yv[sD0], yD1 = yv[sD1];

        const int dmax = deg0 > deg1 ? deg0 : deg1;
        for (int e0 = 0; e0 < dmax; e0 += 8) {
            // prefetch slot E at e0+32+sub
            const int en = e0 + 32 + sub;
            const bool okE0 = en < deg0, okE1 = en < deg1;
            int sE0 = led2[okE0 ? st0 + en : 0]; sE0 = okE0 ? sE0 : 0;
            int sE1 = led2[okE1 ? st1 + en : 0]; sE1 = okE1 ? sE1 : 0;
            const uint2 uE0 = *(const uint2*)(xh + (size_t)sE0 * HID + g * 4);
            const uint2 uE1 = *(const uint2*)(xh + (size_t)sE1 * HID + g * 4);
            const float2 yE0 = yv[sE0], yE1 = yv[sE1];

            // compute with slot A
            {
                const float4 xs = h4_to_f4(uA0);
                float p = xt0.x*xs.x + xt0.y*xs.y + xt0.z*xs.z + xt0.w*xs.w;
                p = dpp_sum8(p);
                const float wgt = okA0 ? __expf(beta * p) : 0.f;
                a00 += wgt * yA0.x; a01 += wgt * yA0.y; ds0 += wgt;
            }
            {
                const float4 xs = h4_to_f4(uA1);
                float p = xt1.x*xs.x + xt1.y*xs.y + xt1.z*xs.z + xt1.w*xs.w;
                p = dpp_sum8(p);
                const float wgt = okA1 ? __expf(beta * p) : 0.f;
                a10 += wgt * yA1.x; a11 += wgt * yA1.y; ds1 += wgt;
            }
            // rotate A<-B<-C<-D<-E
            uA0 = uB0; yA0 = yB0; okA0 = okB0;
            uA1 = uB1; yA1 = yB1; okA1 = okB1;
            uB0 = uC0; yB0 = yC0; okB0 = okC0;
            uB1 = uC1; yB1 = yC1; okB1 = okC1;
            uC0 = uD0; yC0 = yD0; okC0 = okD0;
            uC1 = uD1; yC1 = yD1; okC1 = okD1;
            uD0 = uE0; yD0 = yE0; okD0 = okE0;
            uD1 = uE1; yD1 = yE1; okD1 = okE1;
        }

        // reduce over slots (each g-column holds an identical copy; xor 8/16/32 sums slots)
        #pragma unroll
        for (int m = 8; m <= 32; m <<= 1) {
            ds0 += __shfl_xor(ds0, m, 64); a00 += __shfl_xor(a00, m, 64); a01 += __shfl_xor(a01, m, 64);
            ds1 += __shfl_xor(ds1, m, 64); a10 += __shfl_xor(a10, m, 64); a11 += __shfl_xor(a11, m, 64);
        }

        // self-loop on lane 0: cos(xn,xn)=1 -> w=exp(beta); y_t from L2
        if (lane == 0 && v0) {
            const float2 yt = yv[node0];
            const float wself = __expf(beta);
            const float d = ds0 + wself;
            float l0v = (a00 + wself * yt.x) / d + bb0;
            float l1v = (a01 + wself * yt.y) / d + bb1;
            float m = fmaxf(l0v, l1v);
            float lse = m + __logf(__expf(l0v - m) + __expf(l1v - m));
            out[2 * (size_t)node0]     = l0v - lse;
            out[2 * (size_t)node0 + 1] = l1v - lse;
        }
        if (lane == 0 && v1) {
            const float2 yt = yv[node1];
            const float wself = __expf(beta);
            const float d = ds1 + wself;
            float l0v = (a10 + wself * yt.x) / d + bb0;
            float l1v = (a11 + wself * yt.y) / d + bb1;
            float m = fmaxf(l0v, l1v);
            float lse = m + __logf(__expf(l0v - m) + __expf(l1v - m));
            out[2 * (size_t)node1]     = l0v - lse;
            out[2 * (size_t)node1 + 1] = l1v - lse;
        }
    }
}

extern "C" void kernel_launch(void* const* d_in, const int* in_sizes, int n_in,
                              void* d_out, int out_size, void* d_ws, size_t ws_size,
                              hipStream_t stream) {
    const float* X    = (const float*)d_in[0];
    const float* w1   = (const float*)d_in[1];
    const float* b1   = (const float*)d_in[2];
    const float* beta = (const float*)d_in[3];
    const float* w2   = (const float*)d_in[4];
    const float* b2   = (const float*)d_in[5];
    const int*   ei   = (const int*)d_in[6];

    const int N = in_sizes[0] / NFEAT;        // 100000
    const int E = in_sizes[6] / 2;            // 1600000
    const int NB = (N + LOCB - 1) / LOCB;     // 1563 buckets of 64 nodes
    const int NC = (E + CHUNK - 1) / CHUNK;   // 391 chunks
    const int R  = NB + 1;
    const int nblk1 = (N + 63) / 64;          // 1563 k1 blocks

    char* wsb = (char*)d_ws;
    __half* xhp   = (__half*)wsb;                 wsb += ALIGN256((size_t)N * HID * 2);   // 6.4 MB
    float2* yv    = (float2*)wsb;                 wsb += ALIGN256((size_t)N * 8);         // 0.8 MB
    int*    binned = (int*)wsb;                   wsb += ALIGN256((size_t)E * 4);         // 6.4 MB
    unsigned short* offU = (unsigned short*)wsb;  wsb += ALIGN256((size_t)NC * R * 2);    // 1.2 MB
    float* out = (float*)d_out;

    k_sort<<<NC, 512, 0, stream>>>(ei, binned, offU, E, NB, NC);
    k1<<<nblk1, 256, 0, stream>>>(X, w1, b1, w2, xhp, yv, N);
    k_fused<<<NB, 256, 0, stream>>>(binned, offU, xhp, yv, beta, b2, out, N, NB, NC);
}

// Round 18
// 172.222 us; speedup vs baseline: 1.0203x; 1.0203x over previous
//
#include <hip/hip_runtime.h>
#include <hip/hip_fp16.h>
#include <math.h>

#define HID 32
#define NFEAT 100
#define CHUNK 4096   // edges per sort chunk (391 chunks = sort parallelism, R8 lesson)
#define NCMAX 512    // max chunks (E/CHUNK = 391)
#define NBMAX 1600   // max buckets (N/64 = 1563)
#define LOCB 64      // target nodes per bucket (R11 lesson: 1563 blocks needed for latency hiding)
#define LCAP 1408    // LDS edge capacity per bucket (mean 1024, sd 32 -> +12 sigma)

#define ALIGN256(x) ((((size_t)(x)) + 255) & ~(size_t)255)

typedef _Float16 half8 __attribute__((ext_vector_type(8)));
typedef float f32x4 __attribute__((ext_vector_type(4)));
typedef float f32x2 __attribute__((ext_vector_type(2)));

// fp8 e4m3 (HW cvt, self-consistent encode/decode): 4 fp8 bytes <-> 4 floats
__device__ __forceinline__ float4 fp8x4_to_f4(int u) {
    f32x2 lo = __builtin_amdgcn_cvt_pk_f32_fp8(u, false);
    f32x2 hi = __builtin_amdgcn_cvt_pk_f32_fp8(u, true);
    return make_float4(lo.x, lo.y, hi.x, hi.y);
}

// 8-lane sum reduction via DPP (proven R7-R17); all 8 lanes get the sum.
__device__ __forceinline__ float dpp_sum8(float x) {
    int v = __float_as_int(x);
    x += __int_as_float(__builtin_amdgcn_update_dpp(0, v, 0xB1, 0xF, 0xF, true));
    v = __float_as_int(x);
    x += __int_as_float(__builtin_amdgcn_update_dpp(0, v, 0x4E, 0xF, 0xF, true));
    v = __float_as_int(x);
    x += __int_as_float(__builtin_amdgcn_update_dpp(0, v, 0x141, 0xF, 0xF, true));
    return x;
}

// ================= K1 (MFMA): xq = fp8(x/||x||) [32B/node]; y = (x.w2r0, x.w2r1) fp32 =====
// R17 lesson: xh fp16 (6.4MB) misses L2 on every edge; fp8 (3.2MB) fits per-XCD L2.
__global__ __launch_bounds__(256) void k1(
    const float* __restrict__ X, const float* __restrict__ w1,
    const float* __restrict__ b1, const float* __restrict__ w2,
    int* __restrict__ xq, float2* __restrict__ yv, int N)
{
    __shared__ __align__(16) char smem[26112];
    const int tid = threadIdx.x;
    const int blk = blockIdx.x;
    _Float16* w1h = (_Float16*)smem;              // [32][136]
    _Float16* xsH = (_Float16*)(smem + 8704);     // [64][136]
    {
        int* w1hI = (int*)w1h; int* xsHI = (int*)xsH;
        for (int i = tid; i < 1728; i += 256) {      // zero K-pad: 96 rows * 18 ints
            int row = i / 18, c2 = i % 18;
            if (row < 32) w1hI[row * 68 + 50 + c2] = 0;
            else          xsHI[(row - 32) * 68 + 50 + c2] = 0;
        }
    }
    const float4* w14 = (const float4*)w1;          // 800 float4
    for (int i = tid; i < 800; i += 256) {
        float4 v = w14[i];
        int idx = i * 4, h = idx / NFEAT, k = idx % NFEAT;
        __half2* d = (__half2*)&w1h[h * 136 + k];
        d[0] = __floats2half2_rn(v.x, v.y);
        d[1] = __floats2half2_rn(v.z, v.w);
    }
    const int n0 = blk * 64;
    const float4* X4 = (const float4*)X;            // row = 25 float4
    for (int i = tid; i < 1600; i += 256) {
        int rr = i / 25, qq = i % 25;
        int node = n0 + rr;
        float4 v = (node < N) ? X4[(size_t)node * 25 + qq] : make_float4(0.f, 0.f, 0.f, 0.f);
        __half2* d = (__half2*)&xsH[rr * 136 + qq * 4];
        d[0] = __floats2half2_rn(v.x, v.y);
        d[1] = __floats2half2_rn(v.z, v.w);
    }
    __syncthreads();

    const int lane = tid & 63;
    const int wvv  = tid >> 6;    // node tile 0..3 (16 nodes each)
    const int mrow = lane & 15;
    const int kgrp = lane >> 4;   // 0..3
    const _Float16* bp = &xsH[(wvv * 16 + mrow) * 136 + kgrp * 8];
    const _Float16* a0 = &w1h[mrow * 136 + kgrp * 8];
    const _Float16* a1 = &w1h[(16 + mrow) * 136 + kgrp * 8];
    f32x4 acc0 = {0.f, 0.f, 0.f, 0.f}, acc1 = {0.f, 0.f, 0.f, 0.f};
    #pragma unroll
    for (int ks = 0; ks < 4; ++ks) {
        half8 bf  = *(const half8*)(bp + ks * 32);
        half8 af0 = *(const half8*)(a0 + ks * 32);
        half8 af1 = *(const half8*)(a1 + ks * 32);
        acc0 = __builtin_amdgcn_mfma_f32_16x16x32_f16(af0, bf, acc0, 0, 0, 0);
        acc1 = __builtin_amdgcn_mfma_f32_16x16x32_f16(af1, bf, acc1, 0, 0, 0);
    }
    // D[m][n]: n = lane&15 (node), m = kgrp*4 + reg (h); acc1 -> h+16
    float v[8]; float ssq = 0.f;
    #pragma unroll
    for (int rr = 0; rr < 4; ++rr) {
        v[rr]     = fmaxf(acc0[rr] + b1[kgrp * 4 + rr], 0.f);
        v[4 + rr] = fmaxf(acc1[rr] + b1[16 + kgrp * 4 + rr], 0.f);
        ssq += v[rr] * v[rr] + v[4 + rr] * v[4 + rr];
    }
    ssq += __shfl_xor(ssq, 16, 64);
    ssq += __shfl_xor(ssq, 32, 64);
    const float inv = 1.f / fmaxf(sqrtf(ssq), 1e-12f);

    // y partials: lane holds features kgrp*4+rr and 16+kgrp*4+rr
    float y0 = 0.f, y1 = 0.f;
    #pragma unroll
    for (int rr = 0; rr < 4; ++rr) {
        y0 += v[rr] * w2[kgrp * 4 + rr]       + v[4 + rr] * w2[16 + kgrp * 4 + rr];
        y1 += v[rr] * w2[HID + kgrp * 4 + rr] + v[4 + rr] * w2[HID + 16 + kgrp * 4 + rr];
    }
    y0 += __shfl_xor(y0, 16, 64); y0 += __shfl_xor(y0, 32, 64);
    y1 += __shfl_xor(y1, 16, 64); y1 += __shfl_xor(y1, 32, 64);

    const int node = n0 + wvv * 16 + mrow;
    if (node < N) {
        // pack 8 normalized features -> 2 dwords of fp8 (byte f = feature f)
        int wlo = __builtin_amdgcn_cvt_pk_fp8_f32(v[0] * inv, v[1] * inv, 0, false);
        wlo = __builtin_amdgcn_cvt_pk_fp8_f32(v[2] * inv, v[3] * inv, wlo, true);
        int whi = __builtin_amdgcn_cvt_pk_fp8_f32(v[4] * inv, v[5] * inv, 0, false);
        whi = __builtin_amdgcn_cvt_pk_fp8_f32(v[6] * inv, v[7] * inv, whi, true);
        xq[(size_t)node * 8 + kgrp]     = wlo;   // features kgrp*4..kgrp*4+3
        xq[(size_t)node * 8 + 4 + kgrp] = whi;   // features 16+kgrp*4..16+kgrp*4+3
        if (kgrp == 0) yv[node] = make_float2(y0, y1);
    }
}

// ================= K_sort: chunk-local counting sort, 512 threads =========================
__global__ __launch_bounds__(512) void k_sort(
    const int* __restrict__ ei,
    int* __restrict__ binned, unsigned short* __restrict__ offU,
    int E, int NB, int NC)
{
    __shared__ int tgt[CHUNK];       // 16 KB
    __shared__ int hist[NBMAX];      // 6.4 KB
    __shared__ int off[NBMAX];       // 6.4 KB
    const int tid = threadIdx.x;
    const int c = blockIdx.x;
    const int start = c * CHUNK;
    const int end = min(start + CHUNK, E);
    const int n = end - start;

    for (int b = tid; b < NB; b += 512) hist[b] = 0;
    for (int i = tid * 4; i < n; i += 2048) {
        if (i + 3 < n) {
            int4 t4 = *(const int4*)(ei + E + start + i);
            tgt[i] = t4.x; tgt[i + 1] = t4.y; tgt[i + 2] = t4.z; tgt[i + 3] = t4.w;
        } else {
            for (int k = 0; k < 4 && i + k < n; ++k) tgt[i + k] = ei[E + start + i + k];
        }
    }
    __syncthreads();
    for (int i = tid; i < n; i += 512) atomicAdd(&hist[tgt[i] >> 6], 1);
    __syncthreads();
    if (tid < 64) {   // wave 0: exclusive scan, 64 buckets/round with carry
        int carry = 0;
        for (int rr = 0; rr * 64 < NB; ++rr) {
            int b = rr * 64 + tid;
            int v = (b < NB) ? hist[b] : 0;
            int x = v;
            #pragma unroll
            for (int dd = 1; dd < 64; dd <<= 1) {
                int y = __shfl_up(x, dd, 64);
                if (tid >= dd) x += y;
            }
            if (b < NB) off[b] = carry + x - v;
            carry += __shfl(x, 63, 64);
        }
    }
    __syncthreads();
    const size_t urow = (size_t)c * (NB + 1);
    for (int b = tid; b < NB; b += 512) {
        offU[urow + b] = (unsigned short)off[b];   // coalesced u16 writes
        hist[b] = off[b];                           // reuse as local cursor
    }
    if (tid == 0) offU[urow + NB] = (unsigned short)n;
    __syncthreads();
    for (int i = tid; i < n; i += 512) {
        const int t = tgt[i];
        const int b = t >> 6;
        const int pos = atomicAdd(&hist[b], 1);
        binned[start + pos] = ei[start + i] | ((t & 63) << 17);  // src<2^17, local 6 bits
    }
}

// ===== Fused: fp8-xn gather (L2-resident 3.2MB) + fp32 y; 4-deep pipeline =================
// 256 threads (4 waves) / 64-node bucket; 8 lanes/edge (dword per lane); named slot-states.
__global__ __launch_bounds__(256) void k_fused(
    const int* __restrict__ binned, const unsigned short* __restrict__ offU,
    const int* __restrict__ xq, const float2* __restrict__ yv,
    const float* __restrict__ pbeta, const float* __restrict__ b2,
    float* __restrict__ out, int N, int NB, int NC)
{
    __shared__ unsigned short b0s[NCMAX], b1s[NCMAX];
    __shared__ int seg[NCMAX + 1];
    __shared__ int cnt[LOCB], cur[LOCB];
    __shared__ int led[LCAP], led2[LCAP];
    const int tid  = threadIdx.x;
    const int lane = tid & 63;
    const int wv   = tid >> 6;   // wave 0..3
    const int g    = lane & 7;   // feature slice: fp8 bytes g*4 .. g*4+3 (dword g of 8)
    const int sub  = lane >> 3;  // edge slot 0..7
    const int b    = blockIdx.x;
    const int R    = NB + 1;
    const float beta = *pbeta;
    const float bb0 = b2[0], bb1 = b2[1];

    for (int c = tid; c < NC; c += 256) {
        const size_t base = (size_t)c * R + b;
        b0s[c] = offU[base];
        b1s[c] = offU[base + 1];
    }
    if (tid < LOCB) cnt[tid] = 0;
    __syncthreads();

    // exclusive scan of segment lengths (wave 0)
    if (tid < 64) {
        int carry = 0;
        for (int rr = 0; rr * 64 < NC; ++rr) {
            int c = rr * 64 + tid;
            int v = (c < NC) ? (int)b1s[c] - (int)b0s[c] : 0;
            int x = v;
            #pragma unroll
            for (int dd = 1; dd < 64; dd <<= 1) {
                int y = __shfl_up(x, dd, 64);
                if (tid >= dd) x += y;
            }
            if (c < NC) seg[c] = carry + x - v;
            carry += __shfl(x, 63, 64);
        }
        if (tid == 0) seg[NC] = carry;
    }
    __syncthreads();
    const int sz = min(seg[NC], LCAP);

    // thread-per-segment concat (~2.6 edges/segment)
    for (int c = tid; c < NC; c += 256) {
        const int b0 = (int)b0s[c];
        const int len = (int)b1s[c] - b0;
        const int gbase = c * CHUNK + b0;
        const int sp = seg[c];
        for (int j = 0; j < len; ++j) {
            const int idx = sp + j;
            if (idx < LCAP) {
                const int w = binned[gbase + j];
                led[idx] = w;
                atomicAdd(&cnt[w >> 17], 1);
            }
        }
    }
    __syncthreads();
    if (tid < 64) {   // exclusive scan of 64 counts
        int v = cnt[tid], x = v;
        #pragma unroll
        for (int dd = 1; dd < 64; dd <<= 1) {
            int y = __shfl_up(x, dd, 64);
            if (tid >= dd) x += y;
        }
        cur[tid] = x - v;
    }
    __syncthreads();
    // reorder into led2, grouped by local node
    for (int i = tid; i < sz; i += 256) {
        const int w = led[i];
        const int pos = atomicAdd(&cur[w >> 17], 1);
        led2[pos] = w & 0x1FFFF;
    }
    __syncthreads();

    // dual-node gather, 4-deep pipeline: slots A/B/C/D per chain
    for (int l0 = wv; l0 < 32; l0 += 4) {
        const int l1 = l0 + 32;
        const int node0 = b * LOCB + l0;
        const int node1 = b * LOCB + l1;
        const bool v0 = node0 < N, v1 = node1 < N;
        const int nr0 = v0 ? node0 : N - 1;
        const int nr1 = v1 ? node1 : N - 1;

        const float4 xt0 = fp8x4_to_f4(xq[(size_t)nr0 * 8 + g]);
        const float4 xt1 = fp8x4_to_f4(xq[(size_t)nr1 * 8 + g]);

        const int deg0 = cnt[l0], deg1 = cnt[l1];
        const int st0 = cur[l0] - deg0, st1 = cur[l1] - deg1;

        float ds0 = 0.f, a00 = 0.f, a01 = 0.f;
        float ds1 = 0.f, a10 = 0.f, a11 = 0.f;

        // ---- prologue: load slots A (sub), B (+8), C (+16), D (+24) for both chains ----
        bool okA0 = sub < deg0,      okA1 = sub < deg1;
        bool okB0 = sub + 8 < deg0,  okB1 = sub + 8 < deg1;
        bool okC0 = sub + 16 < deg0, okC1 = sub + 16 < deg1;
        bool okD0 = sub + 24 < deg0, okD1 = sub + 24 < deg1;
        int sA0 = led2[okA0 ? st0 + sub : 0];      sA0 = okA0 ? sA0 : 0;
        int sA1 = led2[okA1 ? st1 + sub : 0];      sA1 = okA1 ? sA1 : 0;
        int sB0 = led2[okB0 ? st0 + sub + 8 : 0];  sB0 = okB0 ? sB0 : 0;
        int sB1 = led2[okB1 ? st1 + sub + 8 : 0];  sB1 = okB1 ? sB1 : 0;
        int sC0 = led2[okC0 ? st0 + sub + 16 : 0]; sC0 = okC0 ? sC0 : 0;
        int sC1 = led2[okC1 ? st1 + sub + 16 : 0]; sC1 = okC1 ? sC1 : 0;
        int sD0 = led2[okD0 ? st0 + sub + 24 : 0]; sD0 = okD0 ? sD0 : 0;
        int sD1 = led2[okD1 ? st1 + sub + 24 : 0]; sD1 = okD1 ? sD1 : 0;
        int uA0 = xq[(size_t)sA0 * 8 + g];
        int uA1 = xq[(size_t)sA1 * 8 + g];
        int uB0 = xq[(size_t)sB0 * 8 + g];
        int uB1 = xq[(size_t)sB1 * 8 + g];
        int uC0 = xq[(size_t)sC0 * 8 + g];
        int uC1 = xq[(size_t)sC1 * 8 + g];
        int uD0 = xq[(size_t)sD0 * 8 + g];
        int uD1 = xq[(size_t)sD1 * 8 + g];
        float2 yA0 = yv[sA0], yA1 = yv[sA1];
        float2 yB0 = yv[sB0], yB1 = yv[sB1];
        float2 yC0 = yv[sC0], yC1 = yv[sC1];
        float2 yD0 = yv[sD0], yD1 = yv[sD1];

        const int dmax = deg0 > deg1 ? deg0 : deg1;
        for (int e0 = 0; e0 < dmax; e0 += 8) {
            // prefetch slot E at e0+32+sub
            const int en = e0 + 32 + sub;
            const bool okE0 = en < deg0, okE1 = en < deg1;
            int sE0 = led2[okE0 ? st0 + en : 0]; sE0 = okE0 ? sE0 : 0;
            int sE1 = led2[okE1 ? st1 + en : 0]; sE1 = okE1 ? sE1 : 0;
            const int uE0 = xq[(size_t)sE0 * 8 + g];
            const int uE1 = xq[(size_t)sE1 * 8 + g];
            const float2 yE0 = yv[sE0], yE1 = yv[sE1];

            // compute with slot A
            {
                const float4 xs = fp8x4_to_f4(uA0);
                float p = xt0.x*xs.x + xt0.y*xs.y + xt0.z*xs.z + xt0.w*xs.w;
                p = dpp_sum8(p);
                const float wgt = okA0 ? __expf(beta * p) : 0.f;
                a00 += wgt * yA0.x; a01 += wgt * yA0.y; ds0 += wgt;
            }
            {
                const float4 xs = fp8x4_to_f4(uA1);
                float p = xt1.x*xs.x + xt1.y*xs.y + xt1.z*xs.z + xt1.w*xs.w;
                p = dpp_sum8(p);
                const float wgt = okA1 ? __expf(beta * p) : 0.f;
                a10 += wgt * yA1.x; a11 += wgt * yA1.y; ds1 += wgt;
            }
            // rotate A<-B<-C<-D<-E
            uA0 = uB0; yA0 = yB0; okA0 = okB0;
            uA1 = uB1; yA1 = yB1; okA1 = okB1;
            uB0 = uC0; yB0 = yC0; okB0 = okC0;
            uB1 = uC1; yB1 = yC1; okB1 = okC1;
            uC0 = uD0; yC0 = yD0; okC0 = okD0;
            uC1 = uD1; yC1 = yD1; okC1 = okD1;
            uD0 = uE0; yD0 = yE0; okD0 = okE0;
            uD1 = uE1; yD1 = yE1; okD1 = okE1;
        }

        // reduce over slots (each g-column holds an identical copy; xor 8/16/32 sums slots)
        #pragma unroll
        for (int m = 8; m <= 32; m <<= 1) {
            ds0 += __shfl_xor(ds0, m, 64); a00 += __shfl_xor(a00, m, 64); a01 += __shfl_xor(a01, m, 64);
            ds1 += __shfl_xor(ds1, m, 64); a10 += __shfl_xor(a10, m, 64); a11 += __shfl_xor(a11, m, 64);
        }

        // self-loop on lane 0: cos(xn,xn)=1 -> w=exp(beta); y_t from L2
        if (lane == 0 && v0) {
            const float2 yt = yv[node0];
            const float wself = __expf(beta);
            const float d = ds0 + wself;
            float l0v = (a00 + wself * yt.x) / d + bb0;
            float l1v = (a01 + wself * yt.y) / d + bb1;
            float m = fmaxf(l0v, l1v);
            float lse = m + __logf(__expf(l0v - m) + __expf(l1v - m));
            out[2 * (size_t)node0]     = l0v - lse;
            out[2 * (size_t)node0 + 1] = l1v - lse;
        }
        if (lane == 0 && v1) {
            const float2 yt = yv[node1];
            const float wself = __expf(beta);
            const float d = ds1 + wself;
            float l0v = (a10 + wself * yt.x) / d + bb0;
            float l1v = (a11 + wself * yt.y) / d + bb1;
            float m = fmaxf(l0v, l1v);
            float lse = m + __logf(__expf(l0v - m) + __expf(l1v - m));
            out[2 * (size_t)node1]     = l0v - lse;
            out[2 * (size_t)node1 + 1] = l1v - lse;
        }
    }
}

extern "C" void kernel_launch(void* const* d_in, const int* in_sizes, int n_in,
                              void* d_out, int out_size, void* d_ws, size_t ws_size,
                              hipStream_t stream) {
    const float* X    = (const float*)d_in[0];
    const float* w1   = (const float*)d_in[1];
    const float* b1   = (const float*)d_in[2];
    const float* beta = (const float*)d_in[3];
    const float* w2   = (const float*)d_in[4];
    const float* b2   = (const float*)d_in[5];
    const int*   ei   = (const int*)d_in[6];

    const int N = in_sizes[0] / NFEAT;        // 100000
    const int E = in_sizes[6] / 2;            // 1600000
    const int NB = (N + LOCB - 1) / LOCB;     // 1563 buckets of 64 nodes
    const int NC = (E + CHUNK - 1) / CHUNK;   // 391 chunks
    const int R  = NB + 1;
    const int nblk1 = (N + 63) / 64;          // 1563 k1 blocks

    char* wsb = (char*)d_ws;
    int*    xqp   = (int*)wsb;                    wsb += ALIGN256((size_t)N * 32);        // 3.2 MB
    float2* yv    = (float2*)wsb;                 wsb += ALIGN256((size_t)N * 8);         // 0.8 MB
    int*    binned = (int*)wsb;                   wsb += ALIGN256((size_t)E * 4);         // 6.4 MB
    unsigned short* offU = (unsigned short*)wsb;  wsb += ALIGN256((size_t)NC * R * 2);    // 1.2 MB
    float* out = (float*)d_out;

    k_sort<<<NC, 512, 0, stream>>>(ei, binned, offU, E, NB, NC);
    k1<<<nblk1, 256, 0, stream>>>(X, w1, b1, w2, xqp, yv, N);
    k_fused<<<NB, 256, 0, stream>>>(binned, offU, xqp, yv, beta, b2, out, N, NB, NC);
}